// Round 2
// baseline (609.304 us; speedup 1.0000x reference)
//
#include <hip/hip_runtime.h>
#include <stdint.h>

#define NB 8192      // tokens
#define ND 2048      // input dim
#define NO 2048      // output dim
#define NE 8         // experts
#define NT (ND / 32) // 64 K-tiles of 32
#define NROWS (2 * NB)          // total (token,expert) assignments: exactly 16384
#define NROWS_PAD (NROWS + 128) // slack so the last expert's tail tile reads in-bounds

typedef __bf16 bf16x8 __attribute__((ext_vector_type(8)));
typedef float floatx4 __attribute__((ext_vector_type(4)));
typedef unsigned short ushort8 __attribute__((ext_vector_type(8)));

__device__ __forceinline__ unsigned short f2bf(float f) {
    union { float f; uint32_t u; } v; v.f = f;
    uint32_t u = v.u;
    return (unsigned short)((u + 0x7FFFu + ((u >> 16) & 1u)) >> 16);  // RNE
}

// Convert expert_w fp32 -> bf16 AND zero the output (atomic-accumulate base).
// Fused to save an enqueue; both are pure streaming.
__global__ __launch_bounds__(256) void cvt_zero_kernel(
        const float* __restrict__ w, unsigned short* __restrict__ ob,
        float* __restrict__ out) {
    const int n4W = NE * NO * ND / 4;
    const int n4O = NB * NO / 4;
    int i = blockIdx.x * blockDim.x + threadIdx.x;
    int stride = gridDim.x * blockDim.x;
    for (; i < n4W + n4O; i += stride) {
        if (i < n4W) {
            float4 v = ((const float4*)w)[i];
            ushort4 o;
            o.x = f2bf(v.x); o.y = f2bf(v.y); o.z = f2bf(v.z); o.w = f2bf(v.w);
            ((ushort4*)ob)[i] = o;
        } else {
            float4 z = {0.f, 0.f, 0.f, 0.f};
            ((float4*)out)[i - n4W] = z;
        }
    }
}

// Phase 1: one wave per token, fp32 logits, top-2 + softmax.
// Block 0 also zeroes the compaction counters (read only by later kernels).
__global__ __launch_bounds__(256) void router_topk_kernel(const float* __restrict__ x,
        const float* __restrict__ rw, const float* __restrict__ rb,
        int* __restrict__ i0a, int* __restrict__ i1a,
        float* __restrict__ w0a, float* __restrict__ w1a,
        int* __restrict__ cnt) {
    if (blockIdx.x == 0 && threadIdx.x < NE) cnt[threadIdx.x] = 0;
    const int wave = threadIdx.x >> 6;
    const int lane = threadIdx.x & 63;
    const int t = blockIdx.x * 4 + wave;
    const float4* xp = (const float4*)(x + (size_t)t * ND);
    const float4* rp = (const float4*)rw;
    float acc[NE];
#pragma unroll
    for (int e = 0; e < NE; e++) acc[e] = 0.f;
#pragma unroll
    for (int i = 0; i < ND / 256; i++) {   // 8 iters: 64 lanes x float4
        int idx = i * 64 + lane;
        float4 xv = xp[idx];
#pragma unroll
        for (int e = 0; e < NE; e++) {
            float4 rv = rp[(size_t)e * (ND / 4) + idx];
            acc[e] += xv.x * rv.x + xv.y * rv.y + xv.z * rv.z + xv.w * rv.w;
        }
    }
#pragma unroll
    for (int e = 0; e < NE; e++) {
        float v = acc[e];
#pragma unroll
        for (int s = 32; s > 0; s >>= 1) v += __shfl_xor(v, s, 64);
        acc[e] = v;
    }
    if (lane == 0) {
        float lg[NE];
#pragma unroll
        for (int e = 0; e < NE; e++) lg[e] = acc[e] + rb[e];
        int i0 = 0; float v0 = lg[0];
#pragma unroll
        for (int e = 1; e < NE; e++) if (lg[e] > v0) { v0 = lg[e]; i0 = e; }  // first-max ties = top_k
        int i1 = -1; float v1 = -3.4e38f;
#pragma unroll
        for (int e = 0; e < NE; e++) if (e != i0 && lg[e] > v1) { v1 = lg[e]; i1 = e; }
        float ex = expf(v1 - v0);
        float inv = 1.f / (1.f + ex);
        i0a[t] = i0; i1a[t] = i1;
        w0a[t] = inv; w1a[t] = ex * inv;
    }
}

// Phase 2: ballot-compaction into ONE combined list per expert (top-1 and
// top-2 together; i0 != i1 so per-expert capacity NB suffices).
__global__ __launch_bounds__(256) void compact_kernel(
        const int* __restrict__ i0a, const int* __restrict__ i1a,
        const float* __restrict__ w0a, const float* __restrict__ w1a,
        int* __restrict__ cnt, int* __restrict__ tok, float* __restrict__ wl) {
    const int lane = threadIdx.x & 63;
    const int gw = (blockIdx.x * 256 + threadIdx.x) >> 6;
    const int t = gw * 64 + lane;
#pragma unroll
    for (int which = 0; which < 2; which++) {
        int sel   = which ? i1a[t] : i0a[t];
        float w   = which ? w1a[t] : w0a[t];
        unsigned long long m[NE];
#pragma unroll
        for (int e = 0; e < NE; e++) m[e] = __ballot(sel == e);
        int slot = __popcll(m[sel] & ((1ull << lane) - 1ull));
        int base = 0;
        if (lane < NE) base = atomicAdd(&cnt[lane], (int)__popcll(m[lane]));
        base = __shfl(base, sel, 64);
        tok[sel * NB + base + slot] = t;
        wl[sel * NB + base + slot]  = w;
    }
}

// Phase 3: pre-gather. Copy each assigned token's x-row ONCE into a densely
// packed bf16 A matrix (expert regions contiguous via prefix over cnt).
// This converts the GEMM's per-K-step random 64B gather (the round-1
// latency bottleneck: ~2000cy effective load latency) into dense
// sequential panel loads. Pad rows beyond NROWS are zero-filled.
__global__ __launch_bounds__(256) void gather_kernel(
        const float* __restrict__ x, const int* __restrict__ cnt,
        const int* __restrict__ tokL, unsigned short* __restrict__ packed) {
    // hoist prefix (cnt is final before this kernel runs)
    int pre[NE + 1];
    pre[0] = 0;
#pragma unroll
    for (int k = 0; k < NE; k++) pre[k + 1] = pre[k] + cnt[k];
    const int CH = ND / 8;   // 256 chunks of 8 elems per row
    int idx = blockIdx.x * blockDim.x + threadIdx.x;
    const int stride = gridDim.x * blockDim.x;
    const int tot = NROWS_PAD * CH;
    for (; idx < tot; idx += stride) {
        int p = idx >> 8;          // packed row
        int c = idx & (CH - 1);    // chunk within row
        int e = -1, r = 0;
#pragma unroll
        for (int k = 0; k < NE; k++)
            if (p >= pre[k] && p < pre[k + 1]) { e = k; r = p - pre[k]; }
        ushort8 o = (ushort8)0;
        if (e >= 0) {
            int tk = tokL[e * NB + r];
            const float4* s = (const float4*)(x + (size_t)tk * ND + c * 8);
            float4 a = s[0], b = s[1];
            o[0] = f2bf(a.x); o[1] = f2bf(a.y); o[2] = f2bf(a.z); o[3] = f2bf(a.w);
            o[4] = f2bf(b.x); o[5] = f2bf(b.y); o[6] = f2bf(b.z); o[7] = f2bf(b.w);
        }
        *(ushort8*)(packed + (size_t)p * ND + c * 8) = o;
    }
}

#define GLL16(g, l) __builtin_amdgcn_global_load_lds( \
    (const __attribute__((address_space(1))) void*)(g), \
    (__attribute__((address_space(3))) void*)(l), 16, 0, 0)

// 128x128 tile GEMM per expert, bf16 MFMA 16x16x32, dense packed A.
// 2-deep software pipeline: 3 LDS buffers, stage tile t+2 while computing
// tile t, counted vmcnt + raw s_barrier (never drain vmcnt(0) mid-loop).
// Output rows collide across experts -> out pre-zeroed, f32 atomicAdd.
__global__ __launch_bounds__(256, 3) void moe_gemm_kernel(
        const unsigned short* __restrict__ packed, const unsigned short* __restrict__ wbf,
        const float* __restrict__ eb, const int* __restrict__ cntArr,
        const int* __restrict__ listTok, const float* __restrict__ listW,
        float* __restrict__ out) {
    __shared__ unsigned short sA[3][128 * 32];
    __shared__ unsigned short sB[3][128 * 32];
    __shared__ int sTok[128];
    __shared__ float sW[128];

    const int e = blockIdx.z, mt = blockIdx.y, nt = blockIdx.x;
    int base = 0;
    for (int i = 0; i < e; i++) base += cntArr[i];   // uniform prefix
    const int cnt = cntArr[e];
    if (mt * 128 >= cnt) return;   // uniform per block
    const int tid = threadIdx.x;
    if (tid < 128) {
        int r = mt * 128 + tid;
        bool ok = r < cnt;
        sTok[tid] = ok ? listTok[e * NB + r] : 0;   // dummy; masked at store
        sW[tid]   = ok ? listW[e * NB + r] : 0.f;
    }
    __syncthreads();

    // staging: 512 chunks of 16B per tile per matrix; 4 GLL16/thread/tile
    const char* gA[2]; const char* gB[2];
    int offAB[2];
#pragma unroll
    for (int r = 0; r < 2; r++) {
        int c = r * 256 + tid;
        int row = c >> 2, colb = (c & 3) * 16;
        gA[r] = (const char*)packed + (size_t)(base + mt * 128 + row) * (ND * 2) + colb;
        gB[r] = (const char*)wbf + ((size_t)e * NO + (size_t)nt * 128 + row) * (ND * 2) + colb;
        offAB[r] = c * 16;   // byte offset inside one LDS buffer
    }

    const int wave = tid >> 6, lane = tid & 63;
    const int wm = (wave >> 1) * 64, wn = (wave & 1) * 64;   // 2x2 wave grid
    const int lr = lane & 15, lq = lane >> 4;
    int roA[4], roB[4];
#pragma unroll
    for (int i = 0; i < 4; i++) {
        roA[i] = (wm + i * 16 + lr) * 32 + lq * 8;
        roB[i] = (wn + i * 16 + lr) * 32 + lq * 8;
    }

    floatx4 acc[4][4];
#pragma unroll
    for (int mi = 0; mi < 4; mi++)
#pragma unroll
        for (int nj = 0; nj < 4; nj++) acc[mi][nj] = (floatx4){0.f, 0.f, 0.f, 0.f};

    // prologue: stage tiles 0 and 1 into buffers 0 and 1
#pragma unroll
    for (int r = 0; r < 2; r++) {
        GLL16(gA[r], (char*)sA[0] + offAB[r]);
        GLL16(gB[r], (char*)sB[0] + offAB[r]);
        gA[r] += 64; gB[r] += 64;
    }
#pragma unroll
    for (int r = 0; r < 2; r++) {
        GLL16(gA[r], (char*)sA[1] + offAB[r]);
        GLL16(gB[r], (char*)sB[1] + offAB[r]);
        gA[r] += 64; gB[r] += 64;
    }

    int cur = 0;
#pragma unroll 1
    for (int t = 0; t < NT; t++) {
        int nxt = cur + 2; if (nxt >= 3) nxt -= 3;
        if (t + 2 < NT) {
#pragma unroll
            for (int r = 0; r < 2; r++) {
                GLL16(gA[r], (char*)sA[nxt] + offAB[r]);
                GLL16(gB[r], (char*)sB[nxt] + offAB[r]);
                gA[r] += 64; gB[r] += 64;
            }
            // 12 outstanding -> wait until tile t's 4 oldest have landed
            asm volatile("s_waitcnt vmcnt(8)" ::: "memory");
        } else if (t + 2 == NT) {
            asm volatile("s_waitcnt vmcnt(4)" ::: "memory");
        } else {
            asm volatile("s_waitcnt vmcnt(0)" ::: "memory");
        }
        __builtin_amdgcn_s_barrier();   // all waves: tile t fully in LDS

        const unsigned short* sAc = sA[cur];
        const unsigned short* sBc = sB[cur];
        bf16x8 af[4], bfr[4];
#pragma unroll
        for (int mi = 0; mi < 4; mi++) af[mi] = *(const bf16x8*)&sAc[roA[mi]];
#pragma unroll
        for (int nj = 0; nj < 4; nj++) bfr[nj] = *(const bf16x8*)&sBc[roB[nj]];
#pragma unroll
        for (int mi = 0; mi < 4; mi++)
#pragma unroll
            for (int nj = 0; nj < 4; nj++)
                acc[mi][nj] = __builtin_amdgcn_mfma_f32_16x16x32_bf16(af[mi], bfr[nj], acc[mi][nj], 0, 0, 0);

        // this wave's LDS reads of buf[cur] done before the barrier:
        // next iteration stages tile t+3 into this same buffer.
        asm volatile("s_waitcnt lgkmcnt(0)" ::: "memory");
        __builtin_amdgcn_s_barrier();
        cur = cur + 1 == 3 ? 0 : cur + 1;
    }

    // epilogue: C/D layout col=lane&15, row=(lane>>4)*4+reg; atomic combine
#pragma unroll
    for (int nj = 0; nj < 4; nj++) {
        int gn = nt * 128 + wn + nj * 16 + lr;
        float bias = eb[(size_t)e * NO + gn];
#pragma unroll
        for (int mi = 0; mi < 4; mi++) {
#pragma unroll
            for (int r = 0; r < 4; r++) {
                int m = wm + mi * 16 + lq * 4 + r;
                if (mt * 128 + m < cnt) {
                    atomicAdd(out + (size_t)sTok[m] * NO + gn,
                              sW[m] * (acc[mi][nj][r] + bias));
                }
            }
        }
    }
}

extern "C" void kernel_launch(void* const* d_in, const int* in_sizes, int n_in,
                              void* d_out, int out_size, void* d_ws, size_t ws_size,
                              hipStream_t stream) {
    const float* x        = (const float*)d_in[0];
    const float* router_w = (const float*)d_in[1];
    const float* router_b = (const float*)d_in[2];
    const float* expert_w = (const float*)d_in[3];
    const float* expert_b = (const float*)d_in[4];
    float* out = (float*)d_out;
    char* ws = (char*)d_ws;

    unsigned short* wbf    = (unsigned short*)ws;                 // 67,108,864 B
    unsigned short* packed = (unsigned short*)(ws + 67108864);    // 16512*4096 = 67,633,152 B
    size_t o = 67108864 + 67633152;                               // 134,742,016
    int*   tokL = (int*)(ws + o);   o += NE * NB * 4;
    float* wL   = (float*)(ws + o); o += NE * NB * 4;
    int*   i0a  = (int*)(ws + o);   o += NB * 4;
    int*   i1a  = (int*)(ws + o);   o += NB * 4;
    float* w0a  = (float*)(ws + o); o += NB * 4;
    float* w1a  = (float*)(ws + o); o += NB * 4;
    int*   cnt  = (int*)(ws + o);   o += 128;
    // total ws use: ~135.4 MB

    router_topk_kernel<<<NB / 4, 256, 0, stream>>>(x, router_w, router_b,
                                                   i0a, i1a, w0a, w1a, cnt);
    cvt_zero_kernel<<<2048, 256, 0, stream>>>(expert_w, wbf, out);
    compact_kernel<<<NB / 64 / 4, 256, 0, stream>>>(i0a, i1a, w0a, w1a, cnt, tokL, wL);
    gather_kernel<<<2048, 256, 0, stream>>>(x, cnt, tokL, packed);
    moe_gemm_kernel<<<dim3(NO / 128, NB / 128, NE), 256, 0, stream>>>(
        packed, wbf, expert_b, cnt, tokL, wL, out);
}

// Round 4
// 575.715 us; speedup vs baseline: 1.0583x; 1.0583x over previous
//
#include <hip/hip_runtime.h>
#include <stdint.h>

#define NB 8192      // tokens
#define ND 2048      // input dim
#define NO 2048      // output dim
#define NE 8         // experts
#define BK 64        // K-tile in bf16 elems (128 B)
#define NT (ND / BK) // 32 K-tiles
#define BM 256
#define BN 256

typedef __bf16 bf16x8 __attribute__((ext_vector_type(8)));
typedef float floatx4 __attribute__((ext_vector_type(4)));

__device__ __forceinline__ unsigned short f2bf(float f) {
    union { float f; uint32_t u; } v; v.f = f;
    uint32_t u = v.u;
    return (unsigned short)((u + 0x7FFFu + ((u >> 16) & 1u)) >> 16);  // RNE
}

// Convert expert_w fp32 -> bf16 AND zero the output (atomic-accumulate base).
__global__ __launch_bounds__(256) void cvt_zero_kernel(
        const float* __restrict__ w, unsigned short* __restrict__ ob,
        float* __restrict__ out) {
    const int n4W = NE * NO * ND / 4;
    const int n4O = NB * NO / 4;
    int i = blockIdx.x * blockDim.x + threadIdx.x;
    int stride = gridDim.x * blockDim.x;
    for (; i < n4W + n4O; i += stride) {
        if (i < n4W) {
            float4 v = ((const float4*)w)[i];
            ushort4 o;
            o.x = f2bf(v.x); o.y = f2bf(v.y); o.z = f2bf(v.z); o.w = f2bf(v.w);
            ((ushort4*)ob)[i] = o;
        } else {
            float4 z = {0.f, 0.f, 0.f, 0.f};
            ((float4*)out)[i - n4W] = z;
        }
    }
}

// Phase 1: one wave per token; fp32 logits, top-2 + softmax, and x->bf16
// (x already streams through; the bf16 copy is free BW-wise).
// Block 0 zeroes the compaction counters.
__global__ __launch_bounds__(256) void router_topk_kernel(const float* __restrict__ x,
        const float* __restrict__ rw, const float* __restrict__ rb,
        unsigned short* __restrict__ xbf,
        int* __restrict__ i0a, int* __restrict__ i1a,
        float* __restrict__ w0a, float* __restrict__ w1a,
        int* __restrict__ cnt) {
    if (blockIdx.x == 0 && threadIdx.x < NE) cnt[threadIdx.x] = 0;
    const int wave = threadIdx.x >> 6;
    const int lane = threadIdx.x & 63;
    const int t = blockIdx.x * 4 + wave;
    const float4* xp = (const float4*)(x + (size_t)t * ND);
    const float4* rp = (const float4*)rw;
    ushort4* xo = (ushort4*)(xbf + (size_t)t * ND);
    float acc[NE];
#pragma unroll
    for (int e = 0; e < NE; e++) acc[e] = 0.f;
#pragma unroll
    for (int i = 0; i < ND / 256; i++) {   // 8 iters: 64 lanes x float4
        int idx = i * 64 + lane;
        float4 xv = xp[idx];
        ushort4 o;
        o.x = f2bf(xv.x); o.y = f2bf(xv.y); o.z = f2bf(xv.z); o.w = f2bf(xv.w);
        xo[idx] = o;
#pragma unroll
        for (int e = 0; e < NE; e++) {
            float4 rv = rp[(size_t)e * (ND / 4) + idx];
            acc[e] += xv.x * rv.x + xv.y * rv.y + xv.z * rv.z + xv.w * rv.w;
        }
    }
#pragma unroll
    for (int e = 0; e < NE; e++) {
        float v = acc[e];
#pragma unroll
        for (int s = 32; s > 0; s >>= 1) v += __shfl_xor(v, s, 64);
        acc[e] = v;
    }
    if (lane == 0) {
        float lg[NE];
#pragma unroll
        for (int e = 0; e < NE; e++) lg[e] = acc[e] + rb[e];
        int i0 = 0; float v0 = lg[0];
#pragma unroll
        for (int e = 1; e < NE; e++) if (lg[e] > v0) { v0 = lg[e]; i0 = e; }  // first-max ties = top_k
        int i1 = -1; float v1 = -3.4e38f;
#pragma unroll
        for (int e = 0; e < NE; e++) if (e != i0 && lg[e] > v1) { v1 = lg[e]; i1 = e; }
        float ex = expf(v1 - v0);
        float inv = 1.f / (1.f + ex);
        i0a[t] = i0; i1a[t] = i1;
        w0a[t] = inv; w1a[t] = ex * inv;
    }
}

// Phase 2: ballot-compaction into ONE combined list per expert.
__global__ __launch_bounds__(256) void compact_kernel(
        const int* __restrict__ i0a, const int* __restrict__ i1a,
        const float* __restrict__ w0a, const float* __restrict__ w1a,
        int* __restrict__ cnt, int* __restrict__ tok, float* __restrict__ wl) {
    const int lane = threadIdx.x & 63;
    const int gw = (blockIdx.x * 256 + threadIdx.x) >> 6;
    const int t = gw * 64 + lane;
#pragma unroll
    for (int which = 0; which < 2; which++) {
        int sel   = which ? i1a[t] : i0a[t];
        float w   = which ? w1a[t] : w0a[t];
        unsigned long long m[NE];
#pragma unroll
        for (int e = 0; e < NE; e++) m[e] = __ballot(sel == e);
        int slot = __popcll(m[sel] & ((1ull << lane) - 1ull));
        int base = 0;
        if (lane < NE) base = atomicAdd(&cnt[lane], (int)__popcll(m[lane]));
        base = __shfl(base, sel, 64);
        tok[sel * NB + base + slot] = t;
        wl[sel * NB + base + slot]  = w;
    }
}

#define GLL16(g, l) __builtin_amdgcn_global_load_lds( \
    (const __attribute__((address_space(1))) void*)(g), \
    (__attribute__((address_space(3))) void*)(l), 16, 0, 0)

// 256x256 tile, BK=64, 512 threads (8 waves: 2M x 4N, 128x64 out per wave).
// Deep-pipeline structure (T3/T4 minimum 2-phase): 2x 64KB LDS dbuf, counted
// vmcnt(8) so staging loads span 2 iterations (never drained mid-loop),
// 64 MFMA per wave per K-tile between one barrier pair.
// T2 swizzle: [row][128B] rows would be a 16-way bank conflict on
// ds_read_b128; XOR bits 4-6 of byte offset with (row&7). global_load_lds
// writes linearly, so the swizzle is applied as inverse-permuted GLOBAL
// source (rule 21: same involution on source and read side).
// T5: setprio(1) around the 32-MFMA clusters.
// LDS = exactly 128 KiB (verified m201 footprint); token list/weights are
// read directly from global (setup: 4 clamped loads; epilogue: L1-broadcast).
__global__ __launch_bounds__(512, 2) void moe_gemm_kernel(
        const unsigned short* __restrict__ xbf, const unsigned short* __restrict__ wbf,
        const float* __restrict__ eb, const int* __restrict__ cntArr,
        const int* __restrict__ listTok, const float* __restrict__ listW,
        float* __restrict__ out) {
    __shared__ unsigned short sA[2][BM * BK];   // 64 KB
    __shared__ unsigned short sB[2][BN * BK];   // 64 KB

    const int e = blockIdx.z, mt = blockIdx.y, nt = blockIdx.x;
    const int cnt = cntArr[e];
    if (mt * BM >= cnt) return;   // uniform per block
    const int tid = threadIdx.x;

    // staging: A tile 256x64 bf16 = 32KB = 2048 16B-chunks; 4/thread. Same B.
    // phys chunk (prow, pcol) holds global column (pcol ^ ((prow&7)<<4)).
    const char* gA[4]; const char* gB[4];
    int ldsOff[4];
#pragma unroll
    for (int i = 0; i < 4; i++) {
        int cid = i * 512 + tid;          // 0..2047
        int prow = cid >> 3;              // 0..255
        int pcol = (cid & 7) * 16;        // byte col 0..112
        int scol = pcol ^ ((prow & 7) << 4);   // inverse-swizzled source col
        int gr = mt * BM + prow;
        int tk = (gr < cnt) ? listTok[e * NB + gr] : 0;   // dummy row; masked at store
        gA[i] = (const char*)xbf + (size_t)tk * (ND * 2) + scol;
        gB[i] = (const char*)wbf + ((size_t)e * NO + (size_t)nt * BN + prow) * (ND * 2) + scol;
        ldsOff[i] = cid * 16;
    }

    const int wave = tid >> 6, lane = tid & 63;
    const int wm = (wave >> 2) * 128;   // wave_m in {0,1}
    const int wn = (wave & 3) * 64;     // wave_n in {0..3}
    const int lr = lane & 15, lq = lane >> 4;
    const int xorv = (lr & 7) << 4;     // row&7 == lr&7 for all frags (16|row-step)
    int roA[8], roB[4];
#pragma unroll
    for (int mi = 0; mi < 8; mi++) roA[mi] = (wm + mi * 16 + lr) * (BK * 2) + ((lq * 16) ^ xorv);
#pragma unroll
    for (int nj = 0; nj < 4; nj++) roB[nj] = (wn + nj * 16 + lr) * (BK * 2) + ((lq * 16) ^ xorv);

    floatx4 acc[8][4];
#pragma unroll
    for (int mi = 0; mi < 8; mi++)
#pragma unroll
        for (int nj = 0; nj < 4; nj++) acc[mi][nj] = (floatx4){0.f, 0.f, 0.f, 0.f};

    // prologue: stage tiles 0 and 1 (8 vmem instr per thread each)
#pragma unroll
    for (int b = 0; b < 2; b++) {
#pragma unroll
        for (int i = 0; i < 4; i++) {
            GLL16(gA[i], (char*)sA[b] + ldsOff[i]);
            GLL16(gB[i], (char*)sB[b] + ldsOff[i]);
            gA[i] += 2 * BK; gB[i] += 2 * BK;
        }
    }

#pragma unroll 1
    for (int t = 0; t < NT; t++) {
        const int cur = t & 1;
        // outstanding: tiles {t, t+1} = 16 -> wait oldest 8 (tile t)
        if (t + 1 < NT) { asm volatile("s_waitcnt vmcnt(8)" ::: "memory"); }
        else           { asm volatile("s_waitcnt vmcnt(0)" ::: "memory"); }
        __builtin_amdgcn_s_barrier();   // tile t fully in LDS, all waves

        const unsigned short* sAc = sA[cur];
        const unsigned short* sBc = sB[cur];
#pragma unroll
        for (int kk = 0; kk < 2; kk++) {
            // kk=1 flips bit 6, which passes through the XOR swizzle
            bf16x8 af[8], bfr[4];
#pragma unroll
            for (int mi = 0; mi < 8; mi++)
                af[mi] = *(const bf16x8*)((const char*)sAc + (roA[mi] ^ (kk * 64)));
#pragma unroll
            for (int nj = 0; nj < 4; nj++)
                bfr[nj] = *(const bf16x8*)((const char*)sBc + (roB[nj] ^ (kk * 64)));
            __builtin_amdgcn_s_setprio(1);
#pragma unroll
            for (int mi = 0; mi < 8; mi++)
#pragma unroll
                for (int nj = 0; nj < 4; nj++)
                    acc[mi][nj] = __builtin_amdgcn_mfma_f32_16x16x32_bf16(af[mi], bfr[nj], acc[mi][nj], 0, 0, 0);
            __builtin_amdgcn_s_setprio(0);
        }

        asm volatile("s_waitcnt lgkmcnt(0)" ::: "memory");
        __builtin_amdgcn_s_barrier();   // all waves done reading buf[cur]
        if (t + 2 < NT) {               // stage tile t+2 into the freed buffer
#pragma unroll
            for (int i = 0; i < 4; i++) {
                GLL16(gA[i], (char*)sA[cur] + ldsOff[i]);
                GLL16(gB[i], (char*)sB[cur] + ldsOff[i]);
                gA[i] += 2 * BK; gB[i] += 2 * BK;
            }
        }
    }

    // epilogue: C/D layout col=lane&15, row=(lane>>4)*4+reg; atomic combine.
    float bias[4];
#pragma unroll
    for (int nj = 0; nj < 4; nj++)
        bias[nj] = eb[(size_t)e * NO + nt * BN + wn + nj * 16 + lr];
#pragma unroll
    for (int mi = 0; mi < 8; mi++) {
#pragma unroll
        for (int r = 0; r < 4; r++) {
            int m = wm + mi * 16 + lq * 4 + r;
            int gr = mt * BM + m;
            if (gr < cnt) {
                int tk   = listTok[e * NB + gr];
                float wg = listW[e * NB + gr];
                float* op = out + (size_t)tk * NO + nt * BN + wn + lr;
#pragma unroll
                for (int nj = 0; nj < 4; nj++)
                    atomicAdd(op + nj * 16, wg * (acc[mi][nj][r] + bias[nj]));
            }
        }
    }
}

extern "C" void kernel_launch(void* const* d_in, const int* in_sizes, int n_in,
                              void* d_out, int out_size, void* d_ws, size_t ws_size,
                              hipStream_t stream) {
    const float* x        = (const float*)d_in[0];
    const float* router_w = (const float*)d_in[1];
    const float* router_b = (const float*)d_in[2];
    const float* expert_w = (const float*)d_in[3];
    const float* expert_b = (const float*)d_in[4];
    float* out = (float*)d_out;
    char* ws = (char*)d_ws;

    unsigned short* xbf = (unsigned short*)ws;                 // 33,554,432 B
    unsigned short* wbf = (unsigned short*)(ws + 33554432);    // 67,108,864 B
    size_t o = 100663296;
    int*   tokL = (int*)(ws + o);   o += NE * NB * 4;
    float* wL   = (float*)(ws + o); o += NE * NB * 4;
    int*   i0a  = (int*)(ws + o);   o += NB * 4;
    int*   i1a  = (int*)(ws + o);   o += NB * 4;
    float* w0a  = (float*)(ws + o); o += NB * 4;
    float* w1a  = (float*)(ws + o); o += NB * 4;
    int*   cnt  = (int*)(ws + o);   o += 128;

    router_topk_kernel<<<NB / 4, 256, 0, stream>>>(x, router_w, router_b, xbf,
                                                   i0a, i1a, w0a, w1a, cnt);
    cvt_zero_kernel<<<2048, 256, 0, stream>>>(expert_w, wbf, out);
    compact_kernel<<<NB / 64 / 4, 256, 0, stream>>>(i0a, i1a, w0a, w1a, cnt, tokL, wL);
    moe_gemm_kernel<<<dim3(NO / BN, NB / BM, NE), 512, 0, stream>>>(
        xbf, wbf, expert_b, cnt, tokL, wL, out);
}

// Round 5
// 557.454 us; speedup vs baseline: 1.0930x; 1.0328x over previous
//
#include <hip/hip_runtime.h>
#include <stdint.h>

#define NB 8192      // tokens
#define ND 2048      // input dim
#define NO 2048      // output dim
#define NE 8         // experts
#define BK 64        // K-tile in bf16 elems (128 B)
#define NT (ND / BK) // 32 K-tiles
#define BM 256
#define BN 256

typedef __bf16 bf16x8 __attribute__((ext_vector_type(8)));
typedef float floatx4 __attribute__((ext_vector_type(4)));

__device__ __forceinline__ unsigned short f2bf(float f) {
    union { float f; uint32_t u; } v; v.f = f;
    uint32_t u = v.u;
    return (unsigned short)((u + 0x7FFFu + ((u >> 16) & 1u)) >> 16);  // RNE
}

// Convert expert_w fp32 -> bf16 AND zero the output (atomic-accumulate base).
__global__ __launch_bounds__(256) void cvt_zero_kernel(
        const float* __restrict__ w, unsigned short* __restrict__ ob,
        float* __restrict__ out) {
    const int n4W = NE * NO * ND / 4;
    const int n4O = NB * NO / 4;
    int i = blockIdx.x * blockDim.x + threadIdx.x;
    int stride = gridDim.x * blockDim.x;
    for (; i < n4W + n4O; i += stride) {
        if (i < n4W) {
            float4 v = ((const float4*)w)[i];
            ushort4 o;
            o.x = f2bf(v.x); o.y = f2bf(v.y); o.z = f2bf(v.z); o.w = f2bf(v.w);
            ((ushort4*)ob)[i] = o;
        } else {
            float4 z = {0.f, 0.f, 0.f, 0.f};
            ((float4*)out)[i - n4W] = z;
        }
    }
}

// Phase 1: one wave per token; fp32 logits, top-2 + softmax, and x->bf16.
__global__ __launch_bounds__(256) void router_topk_kernel(const float* __restrict__ x,
        const float* __restrict__ rw, const float* __restrict__ rb,
        unsigned short* __restrict__ xbf,
        int* __restrict__ i0a, int* __restrict__ i1a,
        float* __restrict__ w0a, float* __restrict__ w1a,
        int* __restrict__ cnt) {
    if (blockIdx.x == 0 && threadIdx.x < NE) cnt[threadIdx.x] = 0;
    const int wave = threadIdx.x >> 6;
    const int lane = threadIdx.x & 63;
    const int t = blockIdx.x * 4 + wave;
    const float4* xp = (const float4*)(x + (size_t)t * ND);
    const float4* rp = (const float4*)rw;
    ushort4* xo = (ushort4*)(xbf + (size_t)t * ND);
    float acc[NE];
#pragma unroll
    for (int e = 0; e < NE; e++) acc[e] = 0.f;
#pragma unroll
    for (int i = 0; i < ND / 256; i++) {
        int idx = i * 64 + lane;
        float4 xv = xp[idx];
        ushort4 o;
        o.x = f2bf(xv.x); o.y = f2bf(xv.y); o.z = f2bf(xv.z); o.w = f2bf(xv.w);
        xo[idx] = o;
#pragma unroll
        for (int e = 0; e < NE; e++) {
            float4 rv = rp[(size_t)e * (ND / 4) + idx];
            acc[e] += xv.x * rv.x + xv.y * rv.y + xv.z * rv.z + xv.w * rv.w;
        }
    }
#pragma unroll
    for (int e = 0; e < NE; e++) {
        float v = acc[e];
#pragma unroll
        for (int s = 32; s > 0; s >>= 1) v += __shfl_xor(v, s, 64);
        acc[e] = v;
    }
    if (lane == 0) {
        float lg[NE];
#pragma unroll
        for (int e = 0; e < NE; e++) lg[e] = acc[e] + rb[e];
        int i0 = 0; float v0 = lg[0];
#pragma unroll
        for (int e = 1; e < NE; e++) if (lg[e] > v0) { v0 = lg[e]; i0 = e; }
        int i1 = -1; float v1 = -3.4e38f;
#pragma unroll
        for (int e = 0; e < NE; e++) if (e != i0 && lg[e] > v1) { v1 = lg[e]; i1 = e; }
        float ex = expf(v1 - v0);
        float inv = 1.f / (1.f + ex);
        i0a[t] = i0; i1a[t] = i1;
        w0a[t] = inv; w1a[t] = ex * inv;
    }
}

// Phase 2: ballot-compaction into ONE combined list per expert.
__global__ __launch_bounds__(256) void compact_kernel(
        const int* __restrict__ i0a, const int* __restrict__ i1a,
        const float* __restrict__ w0a, const float* __restrict__ w1a,
        int* __restrict__ cnt, int* __restrict__ tok, float* __restrict__ wl) {
    const int lane = threadIdx.x & 63;
    const int gw = (blockIdx.x * 256 + threadIdx.x) >> 6;
    const int t = gw * 64 + lane;
#pragma unroll
    for (int which = 0; which < 2; which++) {
        int sel   = which ? i1a[t] : i0a[t];
        float w   = which ? w1a[t] : w0a[t];
        unsigned long long m[NE];
#pragma unroll
        for (int e = 0; e < NE; e++) m[e] = __ballot(sel == e);
        int slot = __popcll(m[sel] & ((1ull << lane) - 1ull));
        int base = 0;
        if (lane < NE) base = atomicAdd(&cnt[lane], (int)__popcll(m[lane]));
        base = __shfl(base, sel, 64);
        tok[sel * NB + base + slot] = t;
        wl[sel * NB + base + slot]  = w;
    }
}

#define GLL16(g, l) __builtin_amdgcn_global_load_lds( \
    (const __attribute__((address_space(1))) void*)(g), \
    (__attribute__((address_space(3))) void*)(l), 16, 0, 0)

#define BAR __builtin_amdgcn_s_barrier()
#define WAITL asm volatile("s_waitcnt lgkmcnt(0)" ::: "memory")

#define LDA(HALFPTR) do {                                                   \
    const char* _p = (const char*)(HALFPTR);                                \
    _Pragma("unroll") for (int mi = 0; mi < 4; mi++)                        \
        _Pragma("unroll") for (int kk = 0; kk < 2; kk++)                    \
            af[mi][kk] = *(const bf16x8*)(_p + offA[mi][kk]);               \
} while (0)

#define LDB(HALFPTR) do {                                                   \
    const char* _p = (const char*)(HALFPTR);                                \
    _Pragma("unroll") for (int nj = 0; nj < 2; nj++)                        \
        _Pragma("unroll") for (int kk = 0; kk < 2; kk++)                    \
            bfr[nj][kk] = *(const bf16x8*)(_p + offB[nj][kk]);              \
} while (0)

#define MMAC(MH, NH) do {                                                   \
    __builtin_amdgcn_s_setprio(1);                                          \
    _Pragma("unroll") for (int kk = 0; kk < 2; kk++)                        \
        _Pragma("unroll") for (int mi = 0; mi < 4; mi++)                    \
            _Pragma("unroll") for (int nj = 0; nj < 2; nj++)                \
                acc[(MH)*4+mi][(NH)*2+nj] =                                 \
                    __builtin_amdgcn_mfma_f32_16x16x32_bf16(                \
                        af[mi][kk], bfr[nj][kk],                            \
                        acc[(MH)*4+mi][(NH)*2+nj], 0, 0, 0);                \
    __builtin_amdgcn_s_setprio(0);                                          \
} while (0)

#define STG_A(D, H, KT) do { if ((KT) < NT) {                               \
    GLL16(bA[H][0] + (size_t)(KT) * 128, (char*)sA[D][H] + tid * 16);       \
    GLL16(bA[H][1] + (size_t)(KT) * 128, (char*)sA[D][H] + 8192 + tid * 16);\
} } while (0)
#define STG_B(D, H, KT) do { if ((KT) < NT) {                               \
    GLL16(bB[H][0] + (size_t)(KT) * 128, (char*)sB[D][H] + tid * 16);       \
    GLL16(bB[H][1] + (size_t)(KT) * 128, (char*)sB[D][H] + 8192 + tid * 16);\
} } while (0)

// 256x256 tile, BK=64, 512 threads (8 waves). 8-phase schedule (T3+T4+T2+T5).
// Each phase = one 128x128 C-quadrant by all 8 waves: {ds_read subtile ||
// stage exactly 1 half-tile -> barrier -> 16 MFMA (setprio) -> lgkm(0) ->
// barrier}. Halves A0/A1/B0/B1 = 128rows x 64cols = 16 KB; 2 dbuf = 128 KiB.
// vmcnt(4) checkpoints only at ends of phases 4 and 8 (2 half-tiles always
// in flight); last iteration drains. Every half's issue-slot -> checkpoint
// -> first-read chain verified; stage targets freed one phase before issue.
__global__ __launch_bounds__(512, 2) void moe_gemm_kernel(
        const unsigned short* __restrict__ xbf, const unsigned short* __restrict__ wbf,
        const float* __restrict__ eb, const int* __restrict__ cntArr,
        const int* __restrict__ listTok, const float* __restrict__ listW,
        float* __restrict__ out) {
    __shared__ unsigned short sA[2][2][128 * 64];
    __shared__ unsigned short sB[2][2][128 * 64];

    const int e = blockIdx.z, mt = blockIdx.y, nt = blockIdx.x;
    const int cnt = cntArr[e];
    if (mt * BM >= cnt) return;
    const int tid = threadIdx.x;

    const int prow0 = tid >> 3;
    const int prow1 = 64 + (tid >> 3);
    const int scol  = ((tid & 7) * 16) ^ (((tid >> 3) & 7) << 4);
    const char* bA[2][2]; const char* bB[2][2];
#pragma unroll
    for (int h = 0; h < 2; h++) {
        int g0 = mt * BM + h * 128 + prow0;
        int g1 = mt * BM + h * 128 + prow1;
        int tk0 = (g0 < cnt) ? listTok[e * NB + g0] : 0;
        int tk1 = (g1 < cnt) ? listTok[e * NB + g1] : 0;
        bA[h][0] = (const char*)xbf + (size_t)tk0 * (ND * 2) + scol;
        bA[h][1] = (const char*)xbf + (size_t)tk1 * (ND * 2) + scol;
        bB[h][0] = (const char*)wbf + ((size_t)e * NO + (size_t)nt * BN + h * 128 + prow0) * (ND * 2) + scol;
        bB[h][1] = (const char*)wbf + ((size_t)e * NO + (size_t)nt * BN + h * 128 + prow1) * (ND * 2) + scol;
    }

    const int wave = tid >> 6, lane = tid & 63;
    const int wm2 = wave >> 2;
    const int wn2 = wave & 3;
    const int lr = lane & 15, lq = lane >> 4;
    const int xorv = (lr & 7) << 4;
    int offA[4][2], offB[2][2];
#pragma unroll
    for (int mi = 0; mi < 4; mi++)
#pragma unroll
        for (int kk = 0; kk < 2; kk++)
            offA[mi][kk] = (wm2 * 64 + mi * 16 + lr) * 128 + ((kk * 64 + lq * 16) ^ xorv);
#pragma unroll
    for (int nj = 0; nj < 2; nj++)
#pragma unroll
        for (int kk = 0; kk < 2; kk++)
            offB[nj][kk] = (wn2 * 32 + nj * 16 + lr) * 128 + ((kk * 64 + lq * 16) ^ xorv);

    bf16x8 af[4][2], bfr[2][2];
    floatx4 acc[8][4];
#pragma unroll
    for (int i = 0; i < 8; i++)
#pragma unroll
        for (int j = 0; j < 4; j++) acc[i][j] = (floatx4){0.f, 0.f, 0.f, 0.f};

    // prologue: tile 0 (4 halves) + tile 1 (A0, B1)
    STG_A(0, 0, 0); STG_B(0, 1, 0); STG_A(0, 1, 0); STG_B(0, 0, 0);
    STG_A(1, 0, 1); STG_B(1, 1, 1);
    asm volatile("s_waitcnt vmcnt(4)" ::: "memory");
    BAR;

#pragma unroll 1
    for (int i = 0; i < NT / 2; i++) {
        const int t1 = 2 * i + 1, t2 = 2 * i + 2, t3 = 2 * i + 3;
        // P1: Q(0,0) d0 | stage A1(t1)->d1
        LDA(sA[0][0]); LDB(sB[0][0]);
        STG_A(1, 1, t1);
        BAR; MMAC(0, 0); WAITL; BAR;
        // P2: Q(0,1) d0 | stage B0(t1)->d1
        LDB(sB[0][1]);
        STG_B(1, 0, t1);
        BAR; MMAC(0, 1); WAITL; BAR;
        // P3: Q(1,1) d0 | stage A0(t2)->d0
        LDA(sA[0][1]);
        STG_A(0, 0, t2);
        BAR; MMAC(1, 1); WAITL; BAR;
        // P4: Q(1,0) d0 | stage B1(t2)->d0 | checkpoint
        LDB(sB[0][0]);
        STG_B(0, 1, t2);
        BAR; MMAC(1, 0); WAITL;
        if (t2 < NT) { asm volatile("s_waitcnt vmcnt(4)" ::: "memory"); }
        else         { asm volatile("s_waitcnt vmcnt(0)" ::: "memory"); }
        BAR;
        // P5: Q(0,0) d1 | stage A1(t2)->d0
        LDA(sA[1][0]); LDB(sB[1][0]);
        STG_A(0, 1, t2);
        BAR; MMAC(0, 0); WAITL; BAR;
        // P6: Q(0,1) d1 | stage B0(t2)->d0
        LDB(sB[1][1]);
        STG_B(0, 0, t2);
        BAR; MMAC(0, 1); WAITL; BAR;
        // P7: Q(1,1) d1 | stage A0(t3)->d1
        LDA(sA[1][1]);
        STG_A(1, 0, t3);
        BAR; MMAC(1, 1); WAITL; BAR;
        // P8: Q(1,0) d1 | stage B1(t3)->d1 | checkpoint
        LDB(sB[1][0]);
        STG_B(1, 1, t3);
        BAR; MMAC(1, 0); WAITL;
        asm volatile("s_waitcnt vmcnt(4)" ::: "memory");
        BAR;
    }

    // epilogue: C/D layout col=lane&15, row=(lane>>4)*4+reg; atomic combine
    float ebv[4];
#pragma unroll
    for (int nh = 0; nh < 2; nh++)
#pragma unroll
        for (int nj = 0; nj < 2; nj++)
            ebv[nh * 2 + nj] = eb[(size_t)e * NO + nt * BN + nh * 128 + wn2 * 32 + nj * 16 + lr];
#pragma unroll
    for (int mh = 0; mh < 2; mh++)
#pragma unroll
    for (int mi = 0; mi < 4; mi++)
#pragma unroll
    for (int r = 0; r < 4; r++) {
        int gr = mt * BM + mh * 128 + wm2 * 64 + mi * 16 + lq * 4 + r;
        if (gr < cnt) {
            int tk   = listTok[e * NB + gr];
            float wg = listW[e * NB + gr];
            float* op = out + (size_t)tk * NO + nt * BN + lr;
#pragma unroll
            for (int nh = 0; nh < 2; nh++)
#pragma unroll
            for (int nj = 0; nj < 2; nj++)
                atomicAdd(op + nh * 128 + wn2 * 32 + nj * 16,
                          wg * (acc[mh * 4 + mi][nh * 2 + nj][r] + ebv[nh * 2 + nj]));
        }
    }
}

extern "C" void kernel_launch(void* const* d_in, const int* in_sizes, int n_in,
                              void* d_out, int out_size, void* d_ws, size_t ws_size,
                              hipStream_t stream) {
    const float* x        = (const float*)d_in[0];
    const float* router_w = (const float*)d_in[1];
    const float* router_b = (const float*)d_in[2];
    const float* expert_w = (const float*)d_in[3];
    const float* expert_b = (const float*)d_in[4];
    float* out = (float*)d_out;
    char* ws = (char*)d_ws;

    unsigned short* xbf = (unsigned short*)ws;                 // 33,554,432 B
    unsigned short* wbf = (unsigned short*)(ws + 33554432);    // 67,108,864 B
    size_t o = 100663296;
    int*   tokL = (int*)(ws + o);   o += NE * NB * 4;
    float* wL   = (float*)(ws + o); o += NE * NB * 4;
    int*   i0a  = (int*)(ws + o);   o += NB * 4;
    int*   i1a  = (int*)(ws + o);   o += NB * 4;
    float* w0a  = (float*)(ws + o); o += NB * 4;
    float* w1a  = (float*)(ws + o); o += NB * 4;
    int*   cnt  = (int*)(ws + o);   o += 128;

    router_topk_kernel<<<NB / 4, 256, 0, stream>>>(x, router_w, router_b, xbf,
                                                   i0a, i1a, w0a, w1a, cnt);
    cvt_zero_kernel<<<2048, 256, 0, stream>>>(expert_w, wbf, out);
    compact_kernel<<<NB / 64 / 4, 256, 0, stream>>>(i0a, i1a, w0a, w1a, cnt, tokL, wL);
    moe_gemm_kernel<<<dim3(NO / BN, NB / BM, NE), 512, 0, stream>>>(
        xbf, wbf, expert_b, cnt, tokL, wL, out);
}